// Round 17
// baseline (106.554 us; speedup 1.0000x reference)
//
#include <hip/hip_runtime.h>
#include <hip/hip_bf16.h>

// B=4, H=W=64 -> N=4096, C=256, d=32
// All MFMA operands stored FRAGMENT-ORDERED so every load is a coalesced
// 1KB wave-load (lane-contiguous base + l*8 shorts).
//
// qF/kF [b][i>>5][f][lane][8] : lane = (i&31)+32*((d>>3)&1), f = d>>4, e = d&7
// vF    [b][i>>4][c>>5][lane][8] : lane = (c&31)+32*((i>>3)&1), e = i&7
// wallF [nf][ks][lane][8] : 16x16x32 B-frags of packed W^T (q|k|v)
// K (and bk) pre-scaled by log2(e): softmax uses v_exp_f32 (2^x) directly.
// 1/Z folded into V by vscale (NOT in-loop — R15: lz loads cost more).
//
// NUMERICS GUARANTEE (R11): every exp2 input clamped to <= 86; fminf
// launders non-finite inputs -> acc provably finite. DO NOT REMOVE.
//
// REGISTER MATH (R16 lesson): 2 waves/SIMD (acc=128 AGPR) leaves ~50% of
// cycles with neither pipe issuing. This kernel: wave owns j64 x c64 ->
// acc = 64 AGPR, VGPR ~100 -> ~164/wave <= 170 (512-reg file / 3) ->
// 12-wave (768-thr) block forces 3 waves/SIMD co-residency.
//
// ws layout (bytes):
//   qF    @ 0          1 MB
//   kF    @ 1 MB       1 MB
//   vF    @ 2 MB       8 MB
//   wallF @ 10 MB      160 KB
//   ball  @ +163840    1.25 KB
//   zpart @ +1280      512 KB   [8][16384] f32
//   rz    @ +524288    64 KB

typedef __attribute__((ext_vector_type(4)))  float    f32x4;
typedef __attribute__((ext_vector_type(16))) float    f32x16;
typedef __attribute__((ext_vector_type(8)))  short    bf8;
typedef __attribute__((ext_vector_type(4)))  short    bf4;
typedef __attribute__((ext_vector_type(4)))  unsigned u32x4;

__device__ __forceinline__ short f2bf(float f) {
    unsigned u = __builtin_bit_cast(unsigned, f);
    u += 0x7FFF + ((u >> 16) & 1);           // RNE
    return (short)(u >> 16);
}
__device__ __forceinline__ float bf2f(short h) {
    unsigned u = ((unsigned)(unsigned short)h) << 16;
    return __builtin_bit_cast(float, u);
}
__device__ __forceinline__ unsigned cvtpk(float lo, float hi) {
    unsigned r;
    asm("v_cvt_pk_bf16_f32 %0, %1, %2" : "=v"(r) : "v"(lo), "v"(hi));
    return r;
}
__device__ __forceinline__ float exp2_fast(float x) {   // 2^x, one v_exp_f32
    float r;
    asm("v_exp_f32 %0, %1" : "=v"(r) : "v"(x));
    return r;
}
__device__ __forceinline__ f32x16 z16() {
    f32x16 v;
#pragma unroll
    for (int i = 0; i < 16; ++i) v[i] = 0.f;
    return v;
}

#define LOG2E 1.44269504088896340736f

// ---------------- K1: pack weights into 16x16x32 B-frag order ---------------
__global__ __launch_bounds__(256) void pack_weights(
    const float* __restrict__ Wq, const float* __restrict__ Wk,
    const float* __restrict__ Wv, const float* __restrict__ bq,
    const float* __restrict__ bk, const float* __restrict__ bv,
    short* __restrict__ wallF, float* __restrict__ ball)
{
    int n = blockIdx.x;        // 0..319
    int k = threadIdx.x;       // 0..255
    float w;
    if (n < 32)       w = Wq[k * 32 + n];
    else if (n < 64)  w = Wk[k * 32 + (n - 32)] * LOG2E;   // fold log2e into K
    else              w = Wv[k * 256 + (n - 64)];
    int nf = n >> 4, lcol = n & 15;
    int ks = k >> 5, lg = (k >> 3) & 3, e = k & 7;
    wallF[((size_t)(nf * 8 + ks) * 64 + lg * 16 + lcol) * 8 + e] = f2bf(w);
    if (k == 0) {
        float bias = (n < 32) ? bq[n] : (n < 64) ? bk[n - 32] * LOG2E : bv[n - 64];
        ball[n] = bias;
    }
}

// ---------------- K2: QKV projection (R15's proven-fastest version) ---------
// Grid 256 (m64 per block), 4 waves x m16; each wave all 20 nf-frags.
__global__ __launch_bounds__(256) void qkv_gemm(
    const float* __restrict__ x, const short* __restrict__ wallF,
    const float* __restrict__ ball,
    short* __restrict__ qf, short* __restrict__ kf, short* __restrict__ vf)
{
    const int w  = threadIdx.x >> 6;
    const int l  = threadIdx.x & 63;
    const int lr = l & 15;             // A row / B col within fragment
    const int lg = l >> 4;             // k-group
    const int m0 = blockIdx.x * 64 + w * 16;

    f32x4 acc[20];
#pragma unroll
    for (int i = 0; i < 20; ++i) acc[i] = (f32x4){0.f, 0.f, 0.f, 0.f};

    const float* xrow = x + (size_t)(m0 + lr) * 256 + lg * 8;

#pragma unroll
    for (int ks = 0; ks < 8; ++ks) {
        f32x4 a0 = *(const f32x4*)(xrow + ks * 32);
        f32x4 a1 = *(const f32x4*)(xrow + ks * 32 + 4);
        bf8 af;
#pragma unroll
        for (int t = 0; t < 4; ++t) { af[t] = f2bf(a0[t]); af[t + 4] = f2bf(a1[t]); }
        const short* wb = wallF + (size_t)ks * 512 + l * 8;
#pragma unroll
        for (int nf = 0; nf < 20; ++nf) {
            bf8 bfr = *(const bf8*)(wb + (size_t)nf * 4096);
            acc[nf] = __builtin_amdgcn_mfma_f32_16x16x32_bf16(af, bfr, acc[nf], 0, 0, 0);
        }
    }

    const int b      = m0 >> 12;
    const int i_base = m0 + lg * 4;          // rows i_base..i_base+3
#pragma unroll
    for (int nf = 0; nf < 20; ++nf) {
        int n = nf * 16 + lr;
        float bias = ball[n];
        if (nf < 4) {          // q (nf<2) / k: d = n & 31
            int d = n & 31;
            int f = (d >> 4) & 1, sub = (d >> 3) & 1, e = d & 7;
            short* dst = (nf < 2) ? qf : kf;
            size_t base = ((size_t)(b * 128 + (i_base >> 5)) * 2 + f) * 512 + 256 * sub + e;
#pragma unroll
            for (int r = 0; r < 4; ++r) {
                int i31 = (i_base + r) & 31;
                dst[base + (size_t)i31 * 8] = f2bf(acc[nf][r] + bias);
            }
        } else {               // v: c = n - 64
            int c = n - 64;
            bf4 pv;
#pragma unroll
            for (int r = 0; r < 4; ++r) pv[r] = f2bf(acc[nf][r] + bias);
            size_t addr = (size_t)(b * 256 + (i_base >> 4)) * 4096
                        + (size_t)(c >> 5) * 512
                        + (size_t)((c & 31) + 32 * ((i_base >> 3) & 1)) * 8
                        + (i_base & 7);
            *(bf4*)(vf + addr) = pv;
        }
    }
}

// ---------------- K3: Z_i = sum_j 2^(q_i . k_j) (R13's 2-tile version) -------
__global__ __launch_bounds__(512) void zsum_kernel(
    const short* __restrict__ qF, const short* __restrict__ kF,
    float* __restrict__ zpart)
{
    const int l = threadIdx.x & 63, w = threadIdx.x >> 6;
    const int b = blockIdx.y;
    const int it0 = blockIdx.x * 2;          // 0,2,..,126

    const short* qpa = qF + (size_t)(b * 128 + it0) * 1024 + l * 8;
    bf8 qa0 = *(const bf8*)(qpa);
    bf8 qa1 = *(const bf8*)(qpa + 512);
    bf8 qb0 = *(const bf8*)(qpa + 1024);
    bf8 qb1 = *(const bf8*)(qpa + 1536);

    float zA = 0.f, zB = 0.f;
    const short* kbase = kF + (size_t)b * 131072 + (size_t)w * 16384 + l * 8;
    for (int jt = 0; jt < 16; ++jt) {
        const short* kp = kbase + jt * 1024;
        bf8 kA0 = *(const bf8*)(kp);
        bf8 kA1 = *(const bf8*)(kp + 512);
        f32x16 SA = z16(), SB = z16();
        SA = __builtin_amdgcn_mfma_f32_32x32x16_bf16(kA0, qa0, SA, 0, 0, 0);
        SA = __builtin_amdgcn_mfma_f32_32x32x16_bf16(kA1, qa1, SA, 0, 0, 0);
        SB = __builtin_amdgcn_mfma_f32_32x32x16_bf16(kA0, qb0, SB, 0, 0, 0);
        SB = __builtin_amdgcn_mfma_f32_32x32x16_bf16(kA1, qb1, SB, 0, 0, 0);
#pragma unroll
        for (int r = 0; r < 16; ++r) {
            zA += exp2_fast(fminf(SA[r], 86.f));   // clamp: finiteness guarantee
            zB += exp2_fast(fminf(SB[r], 86.f));
        }
    }
    zA += __shfl_xor(zA, 32);
    zB += __shfl_xor(zB, 32);
    if (l < 32) {
        zpart[(size_t)w * 16384 + b * 4096 + it0 * 32 + l]      = zA;
        zpart[(size_t)w * 16384 + b * 4096 + it0 * 32 + 32 + l] = zB;
    }
}

// ---------------- K3b: rz = 1 / sum(partials) --------------------------------
__global__ __launch_bounds__(256) void zfinish(
    const float* __restrict__ zpart, float* __restrict__ rz)
{
    int i = blockIdx.x * 256 + threadIdx.x;   // 0..16383
    float z = 0.f;
#pragma unroll
    for (int p = 0; p < 8; ++p) z += zpart[p * 16384 + i];
    rz[i] = 1.0f / z;
}

// ---------------- K4: vs = v / Z  (in place on vF) ---------------------------
__global__ __launch_bounds__(256) void vscale(
    short* __restrict__ vF, const float* __restrict__ rz)
{
    int t = blockIdx.x * 256 + threadIdx.x;      // 0..524287
    size_t base = (size_t)t * 8;
    int b   = (int)(base >> 20);
    int rem = (int)(base & 1048575);
    int it  = rem >> 12;
    int sub = (rem >> 8) & 1;                    // lane>>5
    int i0  = it * 16 + sub * 8;
    bf8 v = *(bf8*)(vF + base);
    const float* rzp = rz + b * 4096 + i0;
    f32x4 r0 = *(const f32x4*)(rzp);
    f32x4 r1 = *(const f32x4*)(rzp + 4);
#pragma unroll
    for (int e = 0; e < 4; ++e) {
        v[e]     = f2bf(bf2f(v[e])     * r0[e]);
        v[e + 4] = f2bf(bf2f(v[e + 4]) * r1[e]);
    }
    *(bf8*)(vF + base) = v;
}

// ---------------- K5: out = gamma * (P^T @ vs) + x ---------------------------
// 12-WAVE / 64-AGPR redesign (R16 lesson): block 768 = 12 waves = (4 wc:
// c64 each) x (3 isub: i stride-3). Wave owns j64 x c64 -> acc 2x2xf32x16
// = 64 AGPR; VGPR ~100 -> 3 waves/SIMD forced by block co-residency.
// Cross-wave softmax: wc0/wc1 produce jf0/jf1 P-frags (2 QK MFMA + 16 exp
// each) into double-buffered LDS; all 4 wc consume both jf. V loads issued
// AFTER the softmax block (keeps them out of the long-lived reg set).
// Raggedness: 128 i-tiles over 3 isub -> 43 lockstep iterations, work
// guarded by m<128 (barrier count uniform).
// Grid 256 = 8 XCD x 32 (1 block/CU): b = xcd>>1, jt = (xcd&1)*32 + k.
__global__ __launch_bounds__(768, 3) void attn_out(
    const short* __restrict__ qF, const short* __restrict__ kF,
    const short* __restrict__ vF,
    const float* __restrict__ x, const float* __restrict__ gammaPtr,
    float* __restrict__ out)
{
    __shared__ short Pb[2][3][2][2][64][8];      // 24 KB [buf][isub][jf][frag][lane][8]
    __shared__ float red[4][64][64];             // 64 KB, epilogue only
    const int l = threadIdx.x & 63, w = threadIdx.x >> 6;
    const int lr = l & 31, hi = l >> 5;
    const int wc = w & 3, isub = w >> 2;         // wc 0..3 (c64); isub 0..2

    const int xcd = blockIdx.x & 7, k = blockIdx.x >> 3;    // k 0..31
    const int b = xcd >> 1;
    const int jt = (xcd & 1) * 32 + k;           // 0..63, j-tile of 64
    const int j0 = jt * 64;
    const int c0 = wc * 64;
    const bool producer = (wc < 2);

    // K frags for own jf (producers only use them; uniform load is harmless)
    const short* kfp = kF + (size_t)(b * 128 + jt * 2 + (wc & 1)) * 1024 + l * 8;
    bf8 kf0 = *(const bf8*)(kfp);
    bf8 kf1 = *(const bf8*)(kfp + 512);

    f32x16 acc[2][2];
#pragma unroll
    for (int jf = 0; jf < 2; ++jf)
#pragma unroll
        for (int cf = 0; cf < 2; ++cf) acc[jf][cf] = z16();

    const short* qbase = qF + (size_t)b * 131072 + l * 8;
    const short* vbase = vF + (size_t)b * 1048576 + (size_t)(c0 >> 5) * 512 + l * 8;

    short* myP = &Pb[0][isub][wc & 1][0][l][0];
    const int PbHalf = 3 * 2 * 2 * 64 * 8;       // shorts per buffer

    // ---- prologue: producers do softmax(m=isub) -> buf0
    if (producer) {
        bf8 q0 = *(const bf8*)(qbase + (size_t)isub * 1024);
        bf8 q1 = *(const bf8*)(qbase + (size_t)isub * 1024 + 512);
        f32x16 S = z16();
        S = __builtin_amdgcn_mfma_f32_32x32x16_bf16(q0, kf0, S, 0, 0, 0);
        S = __builtin_amdgcn_mfma_f32_32x32x16_bf16(q1, kf1, S, 0, 0, 0);
        float p[16];
#pragma unroll
        for (int r = 0; r < 16; ++r) p[r] = exp2_fast(fminf(S[r], 86.f));
        unsigned X0 = cvtpk(p[0],  p[1]),  Y0 = cvtpk(p[4],  p[5]);
        unsigned X1 = cvtpk(p[2],  p[3]),  Y1 = cvtpk(p[6],  p[7]);
        unsigned X2 = cvtpk(p[8],  p[9]),  Y2 = cvtpk(p[12], p[13]);
        unsigned X3 = cvtpk(p[10], p[11]), Y3 = cvtpk(p[14], p[15]);
        asm("v_permlane32_swap_b32 %0, %1" : "+v"(X0), "+v"(Y0));
        asm("v_permlane32_swap_b32 %0, %1" : "+v"(X1), "+v"(Y1));
        asm("v_permlane32_swap_b32 %0, %1" : "+v"(X2), "+v"(Y2));
        asm("v_permlane32_swap_b32 %0, %1" : "+v"(X3), "+v"(Y3));
        u32x4 a0w = {X0, X1, Y0, Y1};
        u32x4 a1w = {X2, X3, Y2, Y3};
        *(bf8*)(myP)       = __builtin_bit_cast(bf8, a0w);
        *(bf8*)(myP + 512) = __builtin_bit_cast(bf8, a1w);
    }

    for (int t = 0; t < 43; ++t) {
        // raw barrier: drain LDS ops only; global loads stay in flight
        asm volatile("s_waitcnt lgkmcnt(0)" ::: "memory");
        __builtin_amdgcn_s_barrier();
        asm volatile("" ::: "memory");

        const int m = isub + t * 3;
        const bool work = (m < 128);
        const int mn = m + 3;

        // PA reads (LDS, issued early; cheap registers)
        bf8 pa00, pa01, pa10, pa11;
        if (work) {
            const short* pb = &Pb[t & 1][isub][0][0][l][0];
            pa00 = *(const bf8*)(pb);             // jf0 ki0
            pa01 = *(const bf8*)(pb + 512);       // jf0 ki1
            pa10 = *(const bf8*)(pb + 1024);      // jf1 ki0
            pa11 = *(const bf8*)(pb + 1536);      // jf1 ki1
        }

        // ---- softmax(t+1) for own jf (producers), write buf[(t+1)&1]
        if (producer && mn < 128) {
            const short* qn = qbase + (size_t)mn * 1024;
            bf8 q0 = *(const bf8*)(qn);
            bf8 q1 = *(const bf8*)(qn + 512);
            f32x16 S = z16();
            S = __builtin_amdgcn_mfma_f32_32x32x16_bf16(q0, kf0, S, 0, 0, 0);
            S = __builtin_amdgcn_mfma_f32_32x32x16_bf16(q1, kf1, S, 0, 0, 0);
            float p[16];
#pragma unroll
            for (int r = 0; r < 16; ++r) p[r] = exp2_fast(fminf(S[r], 86.f));
            unsigned X0 = cvtpk(p[0],  p[1]),  Y0 = cvtpk(p[4],  p[5]);
            unsigned X1 = cvtpk(p[2],  p[3]),  Y1 = cvtpk(p[6],  p[7]);
            unsigned X2 = cvtpk(p[8],  p[9]),  Y2 = cvtpk(p[12], p[13]);
            unsigned X3 = cvtpk(p[10], p[11]), Y3 = cvtpk(p[14], p[15]);
            asm("v_permlane32_swap_b32 %0, %1" : "+v"(X0), "+v"(Y0));
            asm("v_permlane32_swap_b32 %0, %1" : "+v"(X1), "+v"(Y1));
            asm("v_permlane32_swap_b32 %0, %1" : "+v"(X2), "+v"(Y2));
            asm("v_permlane32_swap_b32 %0, %1" : "+v"(X3), "+v"(Y3));
            u32x4 a0w = {X0, X1, Y0, Y1};
            u32x4 a1w = {X2, X3, Y2, Y3};
            short* dst = myP + ((t + 1) & 1) * PbHalf;
            *(bf8*)(dst)       = __builtin_bit_cast(bf8, a0w);
            *(bf8*)(dst + 512) = __builtin_bit_cast(bf8, a1w);
        }

        // ---- V loads + PV(t): 8 MFMA
        if (work) {
            const short* vp = vbase + (size_t)m * 8192;
            bf8 v00  = *(const bf8*)(vp);
            bf8 v01  = *(const bf8*)(vp + 512);
            bf8 cv10 = *(const bf8*)(vp + 4096);
            bf8 cv11 = *(const bf8*)(vp + 4096 + 512);

            __builtin_amdgcn_s_setprio(1);
            acc[0][0] = __builtin_amdgcn_mfma_f32_32x32x16_bf16(pa00, v00,  acc[0][0], 0, 0, 0);
            acc[0][1] = __builtin_amdgcn_mfma_f32_32x32x16_bf16(pa00, v01,  acc[0][1], 0, 0, 0);
            acc[1][0] = __builtin_amdgcn_mfma_f32_32x32x16_bf16(pa10, v00,  acc[1][0], 0, 0, 0);
            acc[1][1] = __builtin_amdgcn_mfma_f32_32x32x16_bf16(pa10, v01,  acc[1][1], 0, 0, 0);
            acc[0][0] = __builtin_amdgcn_mfma_f32_32x32x16_bf16(pa01, cv10, acc[0][0], 0, 0, 0);
            acc[0][1] = __builtin_amdgcn_mfma_f32_32x32x16_bf16(pa01, cv11, acc[0][1], 0, 0, 0);
            acc[1][0] = __builtin_amdgcn_mfma_f32_32x32x16_bf16(pa11, cv10, acc[1][0], 0, 0, 0);
            acc[1][1] = __builtin_amdgcn_mfma_f32_32x32x16_bf16(pa11, cv11, acc[1][1], 0, 0, 0);
            __builtin_amdgcn_s_setprio(0);
        }
    }

    // epilogue: reduce 3 isub partials into isub 0
#pragma unroll
    for (int src = 1; src < 3; ++src) {
        if (isub == src) {
#pragma unroll
            for (int jf = 0; jf < 2; ++jf)
#pragma unroll
                for (int cf = 0; cf < 2; ++cf)
#pragma unroll
                    for (int r = 0; r < 16; ++r) {
                        int jrow = (r & 3) + 8 * (r >> 2) + 4 * hi;
                        red[wc][jf * 32 + jrow][cf * 32 + lr] = acc[jf][cf][r];
                    }
        }
        __syncthreads();
        if (isub == 0) {
#pragma unroll
            for (int jf = 0; jf < 2; ++jf)
#pragma unroll
                for (int cf = 0; cf < 2; ++cf)
#pragma unroll
                    for (int r = 0; r < 16; ++r) {
                        int jrow = (r & 3) + 8 * (r >> 2) + 4 * hi;
                        acc[jf][cf][r] += red[wc][jf * 32 + jrow][cf * 32 + lr];
                    }
        }
        __syncthreads();
    }
    if (isub == 0) {
        const float gamma = *gammaPtr;
#pragma unroll
        for (int jf = 0; jf < 2; ++jf)
#pragma unroll
            for (int cf = 0; cf < 2; ++cf)
#pragma unroll
                for (int r = 0; r < 16; ++r) {
                    int jrow = (r & 3) + 8 * (r >> 2) + 4 * hi;
                    int j = j0 + jf * 32 + jrow;
                    size_t idx = (size_t)(b * 4096 + j) * 256 + c0 + cf * 32 + lr;
                    out[idx] = gamma * acc[jf][cf][r] + x[idx];
                }
    }
}

extern "C" void kernel_launch(void* const* d_in, const int* in_sizes, int n_in,
                              void* d_out, int out_size, void* d_ws, size_t ws_size,
                              hipStream_t stream)
{
    const float* x  = (const float*)d_in[0];
    const float* Wq = (const float*)d_in[1];
    const float* bq = (const float*)d_in[2];
    const float* Wk = (const float*)d_in[3];
    const float* bk = (const float*)d_in[4];
    const float* Wv = (const float*)d_in[5];
    const float* bv = (const float*)d_in[6];
    const float* gm = (const float*)d_in[7];
    float* out = (float*)d_out;

    char* wsb = (char*)d_ws;
    short* qf    = (short*)(wsb);
    short* kf    = (short*)(wsb + (1u << 20));
    short* vf    = (short*)(wsb + (2u << 20));
    short* wallF = (short*)(wsb + (10u << 20));
    float* ball  = (float*)(wsb + (10u << 20) + 163840);
    float* zpart = (float*)(wsb + (10u << 20) + 163840 + 1280);
    float* rz    = (float*)(wsb + (10u << 20) + 163840 + 1280 + 524288);

    pack_weights<<<320, 256, 0, stream>>>(Wq, Wk, Wv, bq, bk, bv, wallF, ball);
    qkv_gemm<<<256, 256, 0, stream>>>(x, wallF, ball, qf, kf, vf);
    zsum_kernel<<<dim3(64, 4), 512, 0, stream>>>(qf, kf, zpart);
    zfinish<<<64, 256, 0, stream>>>(zpart, rz);
    vscale<<<2048, 256, 0, stream>>>(vf, rz);
    attn_out<<<256, 768, 0, stream>>>(qf, kf, vf, x, gm, out);
}

// Round 19
// 87.382 us; speedup vs baseline: 1.2194x; 1.2194x over previous
//
#include <hip/hip_runtime.h>
#include <hip/hip_bf16.h>

// B=4, H=W=64 -> N=4096, C=256, d=32
// All MFMA operands stored FRAGMENT-ORDERED so every load is a coalesced
// 1KB wave-load (lane-contiguous base + l*8 shorts).
//
// qF/kF [b][i>>5][f][lane][8] : lane = (i&31)+32*((d>>3)&1), f = d>>4, e = d&7
// vF    [b][i>>4][c>>5][lane][8] : lane = (c&31)+32*((i>>3)&1), e = i&7
// wallF [nf][ks][lane][8] : 16x16x32 B-frags of packed W^T (q|k|v)
// K (and bk) pre-scaled by log2(e): softmax uses v_exp_f32 (2^x) directly.
// 1/Z folded via lrz = -log2(Z) as the QK MFMA's C-INPUT (zero VALU cost,
// zero extra registers — the lz values ARE the S accumulator init). lrz is
// mirrored into LDS once per block -> broadcast ds_reads, no L2 latency.
// (R15 lesson: global in-loop lz cost +5.5us; R16 lesson: vscale costs 5.7us.)
//
// NUMERICS GUARANTEE (R11): every exp2 input clamped to <= 86; fminf
// launders non-finite inputs -> acc provably finite. DO NOT REMOVE.
//
// ws layout (bytes):
//   qF    @ 0          1 MB
//   kF    @ 1 MB       1 MB
//   vF    @ 2 MB       8 MB
//   wallF @ 10 MB      160 KB
//   ball  @ +163840    1.25 KB
//   zpart @ +1280      512 KB   [8][16384] f32
//   lrz   @ +524288    64 KB    -log2(Z)

typedef __attribute__((ext_vector_type(4)))  float    f32x4;
typedef __attribute__((ext_vector_type(16))) float    f32x16;
typedef __attribute__((ext_vector_type(8)))  short    bf8;
typedef __attribute__((ext_vector_type(4)))  short    bf4;
typedef __attribute__((ext_vector_type(4)))  unsigned u32x4;

__device__ __forceinline__ short f2bf(float f) {
    unsigned u = __builtin_bit_cast(unsigned, f);
    u += 0x7FFF + ((u >> 16) & 1);           // RNE
    return (short)(u >> 16);
}
__device__ __forceinline__ unsigned cvtpk(float lo, float hi) {
    unsigned r;
    asm("v_cvt_pk_bf16_f32 %0, %1, %2" : "=v"(r) : "v"(lo), "v"(hi));
    return r;
}
__device__ __forceinline__ float exp2_fast(float x) {   // 2^x, one v_exp_f32
    float r;
    asm("v_exp_f32 %0, %1" : "=v"(r) : "v"(x));
    return r;
}
__device__ __forceinline__ f32x16 z16() {
    f32x16 v;
#pragma unroll
    for (int i = 0; i < 16; ++i) v[i] = 0.f;
    return v;
}

#define LOG2E 1.44269504088896340736f

// ---------------- K1: pack weights into 16x16x32 B-frag order ---------------
__global__ __launch_bounds__(256) void pack_weights(
    const float* __restrict__ Wq, const float* __restrict__ Wk,
    const float* __restrict__ Wv, const float* __restrict__ bq,
    const float* __restrict__ bk, const float* __restrict__ bv,
    short* __restrict__ wallF, float* __restrict__ ball)
{
    int n = blockIdx.x;        // 0..319
    int k = threadIdx.x;       // 0..255
    float w;
    if (n < 32)       w = Wq[k * 32 + n];
    else if (n < 64)  w = Wk[k * 32 + (n - 32)] * LOG2E;   // fold log2e into K
    else              w = Wv[k * 256 + (n - 64)];
    int nf = n >> 4, lcol = n & 15;
    int ks = k >> 5, lg = (k >> 3) & 3, e = k & 7;
    wallF[((size_t)(nf * 8 + ks) * 64 + lg * 16 + lcol) * 8 + e] = f2bf(w);
    if (k == 0) {
        float bias = (n < 32) ? bq[n] : (n < 64) ? bk[n - 32] * LOG2E : bv[n - 64];
        ball[n] = bias;
    }
}

// ---------------- K2: QKV projection (R15's proven-fastest stack version) ---
// Grid 256 (m64 per block), 4 waves x m16; each wave all 20 nf-frags.
__global__ __launch_bounds__(256) void qkv_gemm(
    const float* __restrict__ x, const short* __restrict__ wallF,
    const float* __restrict__ ball,
    short* __restrict__ qf, short* __restrict__ kf, short* __restrict__ vf)
{
    const int w  = threadIdx.x >> 6;
    const int l  = threadIdx.x & 63;
    const int lr = l & 15;             // A row / B col within fragment
    const int lg = l >> 4;             // k-group
    const int m0 = blockIdx.x * 64 + w * 16;

    f32x4 acc[20];
#pragma unroll
    for (int i = 0; i < 20; ++i) acc[i] = (f32x4){0.f, 0.f, 0.f, 0.f};

    const float* xrow = x + (size_t)(m0 + lr) * 256 + lg * 8;

#pragma unroll
    for (int ks = 0; ks < 8; ++ks) {
        f32x4 a0 = *(const f32x4*)(xrow + ks * 32);
        f32x4 a1 = *(const f32x4*)(xrow + ks * 32 + 4);
        bf8 af;
#pragma unroll
        for (int t = 0; t < 4; ++t) { af[t] = f2bf(a0[t]); af[t + 4] = f2bf(a1[t]); }
        const short* wb = wallF + (size_t)ks * 512 + l * 8;
#pragma unroll
        for (int nf = 0; nf < 20; ++nf) {
            bf8 bfr = *(const bf8*)(wb + (size_t)nf * 4096);
            acc[nf] = __builtin_amdgcn_mfma_f32_16x16x32_bf16(af, bfr, acc[nf], 0, 0, 0);
        }
    }

    const int b      = m0 >> 12;
    const int i_base = m0 + lg * 4;          // rows i_base..i_base+3
#pragma unroll
    for (int nf = 0; nf < 20; ++nf) {
        int n = nf * 16 + lr;
        float bias = ball[n];
        if (nf < 4) {          // q (nf<2) / k: d = n & 31
            int d = n & 31;
            int f = (d >> 4) & 1, sub = (d >> 3) & 1, e = d & 7;
            short* dst = (nf < 2) ? qf : kf;
            size_t base = ((size_t)(b * 128 + (i_base >> 5)) * 2 + f) * 512 + 256 * sub + e;
#pragma unroll
            for (int r = 0; r < 4; ++r) {
                int i31 = (i_base + r) & 31;
                dst[base + (size_t)i31 * 8] = f2bf(acc[nf][r] + bias);
            }
        } else {               // v: c = n - 64
            int c = n - 64;
            bf4 pv;
#pragma unroll
            for (int r = 0; r < 4; ++r) pv[r] = f2bf(acc[nf][r] + bias);
            size_t addr = (size_t)(b * 256 + (i_base >> 4)) * 4096
                        + (size_t)(c >> 5) * 512
                        + (size_t)((c & 31) + 32 * ((i_base >> 3) & 1)) * 8
                        + (i_base & 7);
            *(bf4*)(vf + addr) = pv;
        }
    }
}

// ---------------- K3: Z_i = sum_j 2^(q_i . k_j), swapped operands ------------
// Grid (64,4): 2 q-tiles per block share each streamed K tile.
__global__ __launch_bounds__(512) void zsum_kernel(
    const short* __restrict__ qF, const short* __restrict__ kF,
    float* __restrict__ zpart)
{
    const int l = threadIdx.x & 63, w = threadIdx.x >> 6;
    const int b = blockIdx.y;
    const int it0 = blockIdx.x * 2;          // 0,2,..,126

    const short* qpa = qF + (size_t)(b * 128 + it0) * 1024 + l * 8;
    bf8 qa0 = *(const bf8*)(qpa);
    bf8 qa1 = *(const bf8*)(qpa + 512);
    bf8 qb0 = *(const bf8*)(qpa + 1024);
    bf8 qb1 = *(const bf8*)(qpa + 1536);

    float zA = 0.f, zB = 0.f;
    const short* kbase = kF + (size_t)b * 131072 + (size_t)w * 16384 + l * 8;
    for (int jt = 0; jt < 16; ++jt) {
        const short* kp = kbase + jt * 1024;
        bf8 kA0 = *(const bf8*)(kp);
        bf8 kA1 = *(const bf8*)(kp + 512);
        f32x16 SA = z16(), SB = z16();
        SA = __builtin_amdgcn_mfma_f32_32x32x16_bf16(kA0, qa0, SA, 0, 0, 0);
        SA = __builtin_amdgcn_mfma_f32_32x32x16_bf16(kA1, qa1, SA, 0, 0, 0);
        SB = __builtin_amdgcn_mfma_f32_32x32x16_bf16(kA0, qb0, SB, 0, 0, 0);
        SB = __builtin_amdgcn_mfma_f32_32x32x16_bf16(kA1, qb1, SB, 0, 0, 0);
#pragma unroll
        for (int r = 0; r < 16; ++r) {
            zA += exp2_fast(fminf(SA[r], 86.f));   // clamp: finiteness guarantee
            zB += exp2_fast(fminf(SB[r], 86.f));
        }
    }
    zA += __shfl_xor(zA, 32);
    zB += __shfl_xor(zB, 32);
    if (l < 32) {
        zpart[(size_t)w * 16384 + b * 4096 + it0 * 32 + l]      = zA;
        zpart[(size_t)w * 16384 + b * 4096 + it0 * 32 + 32 + l] = zB;
    }
}

// ---------------- K3b: lrz = -log2(sum of partials) --------------------------
__global__ __launch_bounds__(256) void zfinish(
    const float* __restrict__ zpart, float* __restrict__ lrz)
{
    int i = blockIdx.x * 256 + threadIdx.x;   // 0..16383
    float z = 0.f;
#pragma unroll
    for (int p = 0; p < 8; ++p) z += zpart[p * 16384 + i];
    lrz[i] = -__log2f(z);
}

// ---------------- K5: out = gamma * (P^T @ V) + x ----------------------------
// R16's proven 8-wave structure + LZ-as-C-operand fold:
//   S = mfma(q0,kf0, mfma(q1,kf1, LZ)),  LZ[r] = lrz[i-row]  (from LDS mirror)
//   p = 2^min(S,86)  == exp(e)/Z  -> vscale kernel deleted.
// Cross-wave softmax share: wave wc computes only jf=wc's softmax, publishes
// PA frags to double-buffered LDS; both wc waves read both jf. Raw-barrier
// loop (lgkmcnt-only fence). Grid 256 = 8 XCD x 32 (1 block/CU).
// Block 512 = 8 waves = (2 wc) x (4 isub, stride-4 over 128 i-tiles).
__global__ __launch_bounds__(512) void attn_out(
    const short* __restrict__ qF, const short* __restrict__ kF,
    const short* __restrict__ vF, const float* __restrict__ lrz,
    const float* __restrict__ x, const float* __restrict__ gammaPtr,
    float* __restrict__ out)
{
    __shared__ short Pb[2][4][2][2][64][8];      // 32 KB [buf][isub][jf][frag][lane][8]
    __shared__ float lzs[4096];                  // 16 KB  -log2(Z) for this b
    __shared__ float red[2][64][128];            // 64 KB, epilogue only
    const int l = threadIdx.x & 63, w = threadIdx.x >> 6;
    const int lr = l & 31, hi = l >> 5;
    const int wc = w & 1, isub = w >> 1;         // wc = own jf; isub 0..3

    const int xcd = blockIdx.x & 7, k = blockIdx.x >> 3;    // k 0..31
    const int b = xcd >> 1;
    const int jt = (xcd & 1) * 32 + k;           // 0..63, j-tile of 64
    const int j0 = jt * 64;
    const int c0 = wc * 128;

    // fill lzs (once): 512 threads x 8 f32
    {
        int t8 = threadIdx.x * 8;
        *(f32x4*)&lzs[t8]     = *(const f32x4*)(lrz + b * 4096 + t8);
        *(f32x4*)&lzs[t8 + 4] = *(const f32x4*)(lrz + b * 4096 + t8 + 4);
    }

    // K frags for OWN jf only (16 VGPR)
    const short* kfp = kF + (size_t)(b * 128 + jt * 2 + wc) * 1024 + l * 8;
    bf8 kf0 = *(const bf8*)(kfp);
    bf8 kf1 = *(const bf8*)(kfp + 512);

    f32x16 acc[2][4];
#pragma unroll
    for (int jf = 0; jf < 2; ++jf)
#pragma unroll
        for (int cf = 0; cf < 4; ++cf) acc[jf][cf] = z16();

    const short* qbase = qF + (size_t)b * 131072 + l * 8;
    const short* vbase = vF + (size_t)b * 1048576 + (size_t)(c0 >> 5) * 512 + l * 8;

    short* myP0 = &Pb[0][isub][wc][0][l][0];
    const int PbHalf = 4 * 2 * 2 * 64 * 8;       // shorts per buffer

    __syncthreads();                             // lzs visible

    // ---- prologue: softmax(0) -> LDS buf0; preload V first-quad(0)
    {
        bf8 q0 = *(const bf8*)(qbase + (size_t)isub * 1024);
        bf8 q1 = *(const bf8*)(qbase + (size_t)isub * 1024 + 512);
        const float* lzp = &lzs[isub * 32 + 4 * hi];
        f32x4 z0 = *(const f32x4*)(lzp);
        f32x4 z1 = *(const f32x4*)(lzp + 8);
        f32x4 z2 = *(const f32x4*)(lzp + 16);
        f32x4 z3 = *(const f32x4*)(lzp + 24);
        f32x16 S;
#pragma unroll
        for (int r = 0; r < 4; ++r) {
            S[r]      = z0[r];
            S[r + 4]  = z1[r];
            S[r + 8]  = z2[r];
            S[r + 12] = z3[r];
        }
        S = __builtin_amdgcn_mfma_f32_32x32x16_bf16(q0, kf0, S, 0, 0, 0);
        S = __builtin_amdgcn_mfma_f32_32x32x16_bf16(q1, kf1, S, 0, 0, 0);
        float p[16];
#pragma unroll
        for (int r = 0; r < 16; ++r) p[r] = exp2_fast(fminf(S[r], 86.f));
        unsigned X0 = cvtpk(p[0],  p[1]),  Y0 = cvtpk(p[4],  p[5]);
        unsigned X1 = cvtpk(p[2],  p[3]),  Y1 = cvtpk(p[6],  p[7]);
        unsigned X2 = cvtpk(p[8],  p[9]),  Y2 = cvtpk(p[12], p[13]);
        unsigned X3 = cvtpk(p[10], p[11]), Y3 = cvtpk(p[14], p[15]);
        asm("v_permlane32_swap_b32 %0, %1" : "+v"(X0), "+v"(Y0));
        asm("v_permlane32_swap_b32 %0, %1" : "+v"(X1), "+v"(Y1));
        asm("v_permlane32_swap_b32 %0, %1" : "+v"(X2), "+v"(Y2));
        asm("v_permlane32_swap_b32 %0, %1" : "+v"(X3), "+v"(Y3));
        u32x4 a0w = {X0, X1, Y0, Y1};
        u32x4 a1w = {X2, X3, Y2, Y3};
        *(bf8*)(myP0)       = __builtin_bit_cast(bf8, a0w);
        *(bf8*)(myP0 + 512) = __builtin_bit_cast(bf8, a1w);
    }
    bf8 v0[4];
#pragma unroll
    for (int cf = 0; cf < 4; ++cf)
        v0[cf] = *(const bf8*)(vbase + (size_t)isub * 8192 + cf * 512);

    for (int t = 0; t < 32; ++t) {
        // RAW barrier: drain LDS ops only — global prefetch stays in flight
        asm volatile("s_waitcnt lgkmcnt(0)" ::: "memory");
        __builtin_amdgcn_s_barrier();
        asm volatile("" ::: "memory");

        const int m = isub + t * 4;
        // read both jf's PA frags for step t
        const short* pb = &Pb[t & 1][isub][0][0][l][0];
        bf8 pa00 = *(const bf8*)(pb);             // jf0 frag0
        bf8 pa01 = *(const bf8*)(pb + 512);       // jf0 frag1
        bf8 pa10 = *(const bf8*)(pb + 1024);      // jf1 frag0
        bf8 pa11 = *(const bf8*)(pb + 1536);      // jf1 frag1

        // issue loads: second V quad (t), first V quad (t+1)
        const short* vp = vbase + (size_t)m * 8192;
        bf8 cv1[4];
#pragma unroll
        for (int cf = 0; cf < 4; ++cf)
            cv1[cf] = *(const bf8*)(vp + 4096 + cf * 512);
        bf8 nv0[4];
#pragma unroll
        for (int cf = 0; cf < 4; ++cf) nv0[cf] = v0[cf];
        if (t < 31) {
            const short* vn = vbase + (size_t)(m + 4) * 8192;
#pragma unroll
            for (int cf = 0; cf < 4; ++cf)
                nv0[cf] = *(const bf8*)(vn + cf * 512);
            // ---- softmax(t+1) for own jf, write to buf[(t+1)&1]
            const short* qn = qbase + (size_t)(m + 4) * 1024;
            bf8 q0 = *(const bf8*)(qn);
            bf8 q1 = *(const bf8*)(qn + 512);
            const float* lzp = &lzs[(m + 4) * 32 + 4 * hi];
            f32x4 z0 = *(const f32x4*)(lzp);
            f32x4 z1 = *(const f32x4*)(lzp + 8);
            f32x4 z2 = *(const f32x4*)(lzp + 16);
            f32x4 z3 = *(const f32x4*)(lzp + 24);
            f32x16 S;
#pragma unroll
            for (int r = 0; r < 4; ++r) {
                S[r]      = z0[r];
                S[r + 4]  = z1[r];
                S[r + 8]  = z2[r];
                S[r + 12] = z3[r];
            }
            S = __builtin_amdgcn_mfma_f32_32x32x16_bf16(q0, kf0, S, 0, 0, 0);
            S = __builtin_amdgcn_mfma_f32_32x32x16_bf16(q1, kf1, S, 0, 0, 0);
            float p[16];
#pragma unroll
            for (int r = 0; r < 16; ++r) p[r] = exp2_fast(fminf(S[r], 86.f));
            unsigned X0 = cvtpk(p[0],  p[1]),  Y0 = cvtpk(p[4],  p[5]);
            unsigned X1 = cvtpk(p[2],  p[3]),  Y1 = cvtpk(p[6],  p[7]);
            unsigned X2 = cvtpk(p[8],  p[9]),  Y2 = cvtpk(p[12], p[13]);
            unsigned X3 = cvtpk(p[10], p[11]), Y3 = cvtpk(p[14], p[15]);
            asm("v_permlane32_swap_b32 %0, %1" : "+v"(X0), "+v"(Y0));
            asm("v_permlane32_swap_b32 %0, %1" : "+v"(X1), "+v"(Y1));
            asm("v_permlane32_swap_b32 %0, %1" : "+v"(X2), "+v"(Y2));
            asm("v_permlane32_swap_b32 %0, %1" : "+v"(X3), "+v"(Y3));
            u32x4 a0w = {X0, X1, Y0, Y1};
            u32x4 a1w = {X2, X3, Y2, Y3};
            short* dst = myP0 + ((t + 1) & 1) * PbHalf;
            *(bf8*)(dst)       = __builtin_bit_cast(bf8, a0w);
            *(bf8*)(dst + 512) = __builtin_bit_cast(bf8, a1w);
        }

        // ---- PV(t): 16 MFMA, overlaps the softmax VALU above
        __builtin_amdgcn_s_setprio(1);
#pragma unroll
        for (int cf = 0; cf < 4; ++cf) {
            acc[0][cf] = __builtin_amdgcn_mfma_f32_32x32x16_bf16(pa00, v0[cf],  acc[0][cf], 0, 0, 0);
            acc[0][cf] = __builtin_amdgcn_mfma_f32_32x32x16_bf16(pa01, cv1[cf], acc[0][cf], 0, 0, 0);
            acc[1][cf] = __builtin_amdgcn_mfma_f32_32x32x16_bf16(pa10, v0[cf],  acc[1][cf], 0, 0, 0);
            acc[1][cf] = __builtin_amdgcn_mfma_f32_32x32x16_bf16(pa11, cv1[cf], acc[1][cf], 0, 0, 0);
        }
        __builtin_amdgcn_s_setprio(0);

#pragma unroll
        for (int cf = 0; cf < 4; ++cf) v0[cf] = nv0[cf];
    }

    // epilogue: 3-round reduce of the 4 i-quarter partials into isub 0
#pragma unroll
    for (int src = 1; src < 4; ++src) {
        if (isub == src) {
#pragma unroll
            for (int jf = 0; jf < 2; ++jf)
#pragma unroll
                for (int cf = 0; cf < 4; ++cf)
#pragma unroll
                    for (int r = 0; r < 16; ++r) {
                        int jrow = (r & 3) + 8 * (r >> 2) + 4 * hi;
                        red[wc][jf * 32 + jrow][cf * 32 + lr] = acc[jf][cf][r];
                    }
        }
        __syncthreads();
        if (isub == 0) {
#pragma unroll
            for (int jf = 0; jf < 2; ++jf)
#pragma unroll
                for (int cf = 0; cf < 4; ++cf)
#pragma unroll
                    for (int r = 0; r < 16; ++r) {
                        int jrow = (r & 3) + 8 * (r >> 2) + 4 * hi;
                        acc[jf][cf][r] += red[wc][jf * 32 + jrow][cf * 32 + lr];
                    }
        }
        __syncthreads();
    }
    if (isub == 0) {
        const float gamma = *gammaPtr;
#pragma unroll
        for (int jf = 0; jf < 2; ++jf)
#pragma unroll
            for (int cf = 0; cf < 4; ++cf)
#pragma unroll
                for (int r = 0; r < 16; ++r) {
                    int jrow = (r & 3) + 8 * (r >> 2) + 4 * hi;
                    int j = j0 + jf * 32 + jrow;
                    size_t idx = (size_t)(b * 4096 + j) * 256 + c0 + cf * 32 + lr;
                    out[idx] = gamma * acc[jf][cf][r] + x[idx];
                }
    }
}

extern "C" void kernel_launch(void* const* d_in, const int* in_sizes, int n_in,
                              void* d_out, int out_size, void* d_ws, size_t ws_size,
                              hipStream_t stream)
{
    const float* x  = (const float*)d_in[0];
    const float* Wq = (const float*)d_in[1];
    const float* bq = (const float*)d_in[2];
    const float* Wk = (const float*)d_in[3];
    const float* bk = (const float*)d_in[4];
    const float* Wv = (const float*)d_in[5];
    const float* bv = (const float*)d_in[6];
    const float* gm = (const float*)d_in[7];
    float* out = (float*)d_out;

    char* wsb = (char*)d_ws;
    short* qf    = (short*)(wsb);
    short* kf    = (short*)(wsb + (1u << 20));
    short* vf    = (short*)(wsb + (2u << 20));
    short* wallF = (short*)(wsb + (10u << 20));
    float* ball  = (float*)(wsb + (10u << 20) + 163840);
    float* zpart = (float*)(wsb + (10u << 20) + 163840 + 1280);
    float* lrz   = (float*)(wsb + (10u << 20) + 163840 + 1280 + 524288);

    pack_weights<<<320, 256, 0, stream>>>(Wq, Wk, Wv, bq, bk, bv, wallF, ball);
    qkv_gemm<<<256, 256, 0, stream>>>(x, wallF, ball, qf, kf, vf);
    zsum_kernel<<<dim3(64, 4), 512, 0, stream>>>(qf, kf, zpart);
    zfinish<<<64, 256, 0, stream>>>(zpart, lrz);
    attn_out<<<256, 512, 0, stream>>>(qf, kf, vf, lrz, x, gm, out);
}